// Round 21
// baseline (198.948 us; speedup 1.0000x reference)
//
#include <hip/hip_runtime.h>
#include <math.h>

// Per-batch MLP 2->36->36->36->1 (sin,sin,sin,softplus) on MFMA, round 21.
// x: (65536,2) f32; params: (32,2809) f32; out: (32,65536) f32.
//
// Formulation per 32-point tile: D = W * h^T, v_mfma_f32_32x32x16_bf16.
// D layout (HW-verified): col=lane&31 (point), feat=(r&3)+8*(r>>2)+4*(lane>>5).
//
// Round-21: THE 64-VGPR BAND. r20 decode: VGPR=80 > 64-band edge caps
// residency at 4 waves/SIMD regardless of supply (m69 banding) -- that's why
// extra blocks didn't help. One-band squeeze (NOT r14's two-band jump):
//  (1) W4 (20 persistent f32/lane) moved to LDS table [20][64] (lane-indexed
//      -> 2-way bank = free). Values/order bit-identical.
//  (2) Serial tiles restored (r16 interleave proven neutral; halves transient
//      acc pressure 64->32).
//  (3) __launch_bounds__(512, 8): forces VGPR <= 64 -> 8 waves/SIMD band.
//  (4) ITERS=4: 1024 blocks = 4 blocks/CU supply to FILL the band.
// Decode: 30-37 confirmed; FETCH explosion/dur>50 spill -> revert to r19
// final; ~41 with VGPR=64 -> intra-chain floor -> declare roofline.
// Frozen: RTZ pk2 (r12), INV2PI fold + v_sin revolutions (r13), plsw,
// LDS frag build, x prefetch (r19), f32 final dot, softplus via __logf.
// Condemned: cvt_pk_bf16, (256,8) bound, poly/hybrid sin.

#define NPTS   65536
#define NBATCH 32
#define NPAR   2809
#define ITERS  4       // points per wave = 64 * ITERS
#define BLOCK  512
#define WPB    (BLOCK / 64)    // waves per block = 8
#define INV2PI 0.15915494309189535f

typedef float        f32x16 __attribute__((ext_vector_type(16)));
typedef short        bf16x8 __attribute__((ext_vector_type(8)));
typedef unsigned int u32;
typedef unsigned int u32x2 __attribute__((ext_vector_type(2)));

// 1-inst pack {bf16_rtz(lo), bf16_rtz(hi)} (r12-proven)
static __device__ __forceinline__ u32 pk2(float lo, float hi)
{
    return __builtin_amdgcn_perm(__float_as_uint(hi), __float_as_uint(lo),
                                 0x07060302u);
}

// raw v_sin_f32: sin(2*pi*y), y in revolutions (|y| <= ~0.65 here)
static __device__ __forceinline__ float sin_rev(float y)
{ return __builtin_amdgcn_sinf(y); }

// swap a's hi-32-lanes with b's lo-32-lanes (proven rounds 6-20)
static __device__ __forceinline__ u32x2 plsw(u32 a, u32 b)
{ return __builtin_amdgcn_permlane32_swap(a, b, false, false); }

static __device__ __forceinline__ bf16x8 mkfrag(u32 w0, u32 w1, u32 w2, u32 w3)
{
    union { u32 u[4]; bf16x8 v; } c;
    c.u[0] = w0; c.u[1] = w1; c.u[2] = w2; c.u[3] = w3;
    return c.v;
}
static __device__ __forceinline__ bf16x8 u4frag(uint4 u)
{ union { uint4 a; bf16x8 v; } c; c.a = u; return c.v; }

static __device__ __forceinline__ f32x16 mfma(bf16x8 a, bf16x8 b, f32x16 c)
{ return __builtin_amdgcn_mfma_f32_32x32x16_bf16(a, b, c, 0, 0, 0); }

// stable softplus; 1+t in (1,2] -> __logf exact there (round-8 proven)
static __device__ __forceinline__ float softplus(float a)
{ return fmaxf(a, 0.0f) + __logf(1.0f + __expf(-fabsf(a))); }

// ---- per-slot weight-fragment gather (r13 fold) -----------------------------

static __device__ __forceinline__ uint4 build_frag_slot(
    const float* __restrict__ pp, int f, int l)
{
    const int c31 = l & 31;
    const int g   = l >> 5;
    float tv[8];
#pragma unroll
    for (int j = 0; j < 8; ++j) tv[j] = 0.0f;

    if (f < 12) {
        const int L = f / 6, t = (f % 6) / 3, s = f % 3;
        const int wb = 108 + L * 1332;
        const int r  = c31 + 32 * t;                 // outfeat row
        if (r < 36) {
#pragma unroll
            for (int j = 0; j < 8; ++j) {
                const int i = 16 * s + 8 * g + j;    // infeat (k)
                if (i < 36)       tv[j] = pp[wb + 36 * r + i] * INV2PI;
                else if (i == 36) tv[j] = pp[wb + 1296 + r] * INV2PI;  // bias
            }
        }
    } else {
        const int t = f - 12;                        // layer-1 tile
        const int r = c31 + 32 * t;
        if (r < 36 && g == 0) {
            tv[0] = pp[2 * r]     * INV2PI;   // k=0: w_x
            tv[1] = pp[2 * r + 1] * INV2PI;   // k=1: w_y
            tv[2] = pp[72 + r]    * INV2PI;   // k=2: bias (h=1 slot)
        }
    }
    uint4 o;
    o.x = pk2(tv[0], tv[1]); o.y = pk2(tv[2], tv[3]);
    o.z = pk2(tv[4], tv[5]); o.w = pk2(tv[6], tv[7]);
    return o;
}

// ---- B-fragment builder: sin(D) -> next-layer B frag (all v_sin) ------------

static __device__ __forceinline__ void buildB(const f32x16& d1, const f32x16& d2,
                                              u32 biasw, u32 (&F)[12])
{
    float s1[16];
#pragma unroll
    for (int r = 0; r < 16; ++r) s1[r] = sin_rev(d1[r]);
    u32 c[8];
#pragma unroll
    for (int q = 0; q < 8; ++q) c[q] = pk2(s1[2 * q], s1[2 * q + 1]);
    const u32 q0 = pk2(sin_rev(d2[0]), sin_rev(d2[1]));
    const u32 q1 = pk2(sin_rev(d2[2]), sin_rev(d2[3]));

    u32x2 r;
    r = plsw(c[0], c[2]); F[0] = r.x; F[2] = r.y;   // kstep0
    r = plsw(c[1], c[3]); F[1] = r.x; F[3] = r.y;
    r = plsw(c[4], c[6]); F[4] = r.x; F[6] = r.y;   // kstep1
    r = plsw(c[5], c[7]); F[5] = r.x; F[7] = r.y;
    F[8] = q0; F[9] = q1; F[10] = biasw; F[11] = 0; // kstep2
}

// ---- one point-tile: L1 mfma -> L2 -> L3 -> final on VALU (W4 from LDS) -----
// w4c = &lds_w4[lane]; w4c[r*64] = this lane's final-layer weight for reg r.

static __device__ __forceinline__ float tile_forward(
    const uint4 (&W)[12], bf16x8 w1a, bf16x8 w1b, bf16x8 bl1,
    const float* w4c, float b4, u32 biasw, const f32x16& z)
{
    // layer 1 (K=3 in one kstep); D in revolutions
    f32x16 d1 = mfma(w1a, bl1, z);
    f32x16 d2 = mfma(w1b, bl1, z);

    // layer 2 (frags 0..5)
    u32 F[12];
    buildB(d1, d2, biasw, F);
    d1 = z; d2 = z;
#pragma unroll
    for (int s = 0; s < 3; ++s) {
        const bf16x8 bf = mkfrag(F[4*s], F[4*s+1], F[4*s+2], F[4*s+3]);
        d1 = mfma(u4frag(W[s]),     bf, d1);
        d2 = mfma(u4frag(W[3 + s]), bf, d2);
    }
    // layer 3 (frags 6..11)
    u32 F2[12];
    buildB(d1, d2, biasw, F2);
    d1 = z; d2 = z;
#pragma unroll
    for (int s = 0; s < 3; ++s) {
        const bf16x8 bf = mkfrag(F2[4*s], F2[4*s+1], F2[4*s+2], F2[4*s+3]);
        d1 = mfma(u4frag(W[6 + s]), bf, d1);
        d2 = mfma(u4frag(W[9 + s]), bf, d2);
    }
    // final layer on VALU: sin#3 (rev) + f32 dot over this lane's feats
    float a0 = 0.0f, a1 = 0.0f;
#pragma unroll
    for (int r = 0; r < 16; r += 2) {
        a0 = fmaf(w4c[r * 64],       sin_rev(d1[r]),     a0);
        a1 = fmaf(w4c[(r + 1) * 64], sin_rev(d1[r + 1]), a1);
    }
#pragma unroll
    for (int r = 0; r < 4; r += 2) {
        a0 = fmaf(w4c[(16 + r) * 64], sin_rev(d2[r]),     a0);
        a1 = fmaf(w4c[(17 + r) * 64], sin_rev(d2[r + 1]), a1);
    }
    const float part = a0 + a1;
    // pair-reduce: lane l (<32) adds partner l+32's partial
    const u32x2 t = plsw(__float_as_uint(part), __float_as_uint(part));
    const float tot = part + __uint_as_float(t.y) + b4;
    return softplus(tot);   // valid at g0 lanes
}

// ---- main kernel ------------------------------------------------------------

__global__ __launch_bounds__(BLOCK, 8) void mlp_mfma_kernel(
    const float* __restrict__ x,
    const float* __restrict__ params,     // original (32,2809)
    float* __restrict__ out)
{
    __shared__ uint4 lds_fw[14 * 64];
    __shared__ float lds_w4[20 * 64];     // [r][lane]; lane-indexed -> 2-way bank

    const int lane = threadIdx.x & 63;
    const int wave = threadIdx.x >> 6;
    const int b    = blockIdx.y;

    const float* pp = params + (size_t)b * NPAR;

    // ---- phase 0: cooperative frag + W4-table build into LDS ----
#pragma unroll
    for (int k = 0; k < 2; ++k) {
        const int sid = threadIdx.x + BLOCK * k;   // 0..1023; 896 real slots
        if (sid < 896)
            lds_fw[sid] = build_frag_slot(pp, sid >> 6, sid & 63);
    }
#pragma unroll
    for (int k = 0; k < 3; ++k) {
        const int sid = threadIdx.x + BLOCK * k;   // 0..1535; 1280 real slots
        if (sid < 1280) {
            const int r  = sid >> 6;
            const int l  = sid & 63;
            const int gg = l >> 5;
            float v = 0.0f;
            if (r < 16)       v = pp[2772 + ((r & 3) + 8 * (r >> 2) + 4 * gg)];
            else if (gg == 0) v = pp[2772 + 32 + (r - 16)];
            lds_w4[sid] = v;
        }
    }
    __syncthreads();

    uint4 W[12];
#pragma unroll
    for (int f = 0; f < 12; ++f)
        W[f] = lds_fw[f * 64 + lane];
    const bf16x8 w1a = u4frag(lds_fw[12 * 64 + lane]);
    const bf16x8 w1b = u4frag(lds_fw[13 * 64 + lane]);
    const float* w4c = &lds_w4[lane];

    const float b4 = pp[2808];
    const u32 biasw = pk2(1.0f, 0.0f);

    f32x16 z;
#pragma unroll
    for (int i = 0; i < 16; ++i) z[i] = 0.0f;

    // ---- x-load software pipeline (r19): iter+1's load before iter's use ----
    const int nbase = blockIdx.x * (64 * ITERS * WPB) + wave * (64 * ITERS) + lane;
    const float2* xp = reinterpret_cast<const float2*>(x);

    float2 xv = xp[nbase];

#pragma unroll 1
    for (int it = 0; it < ITERS; ++it) {
        // prefetch next iter's point (clamped re-load of same on last iter)
        const int itn = (it + 1 < ITERS) ? it + 1 : it;
        const float2 xvn = xp[nbase + itn * 64];

        // layer-1 B frags: own point (tile A) / partner's point (tile B).
        const u32 pxy  = pk2(xv.x, xv.y);
        const u32 pxyB = plsw(pxy, pxy).y;

        const float spA = tile_forward(W, w1a, w1b, mkfrag(pxy,  biasw, 0, 0),
                                       w4c, b4, biasw, z);
        const float spB = tile_forward(W, w1a, w1b, mkfrag(pxyB, biasw, 0, 0),
                                       w4c, b4, biasw, z);

        // merged store (tile A -> lanes 0..31, B -> 32..63)
        const u32x2 r = plsw(__float_as_uint(spA), __float_as_uint(spB));
        out[(size_t)b * NPTS + nbase + it * 64] = __uint_as_float(r.x);
        xv = xvn;
    }
}

extern "C" void kernel_launch(void* const* d_in, const int* in_sizes, int n_in,
                              void* d_out, int out_size, void* d_ws, size_t ws_size,
                              hipStream_t stream)
{
    const float* x = (const float*)d_in[0];
    const float* params = (const float*)d_in[1];
    float* out = (float*)d_out;

    mlp_mfma_kernel<<<dim3(NPTS / (64 * ITERS * WPB), NBATCH), dim3(BLOCK), 0, stream>>>(
        x, params, out);
}

// Round 22
// 45.447 us; speedup vs baseline: 4.3775x; 4.3775x over previous
//
#include <hip/hip_runtime.h>
#include <math.h>

// Per-batch MLP 2->36->36->36->1 (sin,sin,sin,softplus) on MFMA, round 22.
// x: (65536,2) f32; params: (32,2809) f32; out: (32,65536) f32.
//
// Formulation per 32-point tile: D = W * h^T, v_mfma_f32_32x32x16_bf16.
// D layout (HW-verified): col=lane&31 (point), feat=(r&3)+8*(r>>2)+4*(lane>>5).
//
// Round-22: REACH THE 64-VGPR BAND NATURALLY. launch_bounds forcing is
// condemned (r14 & r21 both made the allocator jump to VGPR=32 -> 500MB
// spill), but r21's occupancy DID double -- the band theory is sound, only
// the mechanism was broken. Register census at r19 (VGPR=80): W[12] frags
// = 48 persistent regs. Changes:
//  (1) Mid-layer frags stay in LDS; read at point of use (ds_read_b128,
//      [f*64+lane] -> 16B/lane consecutive = bank-conflict-free). -48 regs.
//  (2) W4 from LDS table (r21 part that worked), serial tiles (r9-proven).
//  (3) NO launch_bounds forcing; BLOCK=512, ITERS=4 -> 1024 blocks =
//      4 blocks/CU = 8 waves/SIMD supply to fill the band if VGPR<=64.
// Peak live ~60 regs -> compiler should land <=64 naturally.
// Decode: VGPR<=64 & 26-36us confirmed; VGPR<=64 & ~40us -> occupancy not
// binding -> roofline; VGPR>64 -> r19 is the floor; FETCH explosion -> spill.
// Frozen: RTZ pk2 (r12), INV2PI fold + v_sin revolutions (r13), plsw,
// LDS frag build, x prefetch (r19), f32 final dot, softplus via __logf.
// Condemned: cvt_pk_bf16, launch_bounds-forcing, poly/hybrid sin.

#define NPTS   65536
#define NBATCH 32
#define NPAR   2809
#define ITERS  4       // points per wave = 64 * ITERS
#define BLOCK  512
#define WPB    (BLOCK / 64)    // waves per block = 8
#define INV2PI 0.15915494309189535f

typedef float        f32x16 __attribute__((ext_vector_type(16)));
typedef short        bf16x8 __attribute__((ext_vector_type(8)));
typedef unsigned int u32;
typedef unsigned int u32x2 __attribute__((ext_vector_type(2)));

// 1-inst pack {bf16_rtz(lo), bf16_rtz(hi)} (r12-proven)
static __device__ __forceinline__ u32 pk2(float lo, float hi)
{
    return __builtin_amdgcn_perm(__float_as_uint(hi), __float_as_uint(lo),
                                 0x07060302u);
}

// raw v_sin_f32: sin(2*pi*y), y in revolutions (|y| <= ~0.65 here)
static __device__ __forceinline__ float sin_rev(float y)
{ return __builtin_amdgcn_sinf(y); }

// swap a's hi-32-lanes with b's lo-32-lanes (proven rounds 6-21)
static __device__ __forceinline__ u32x2 plsw(u32 a, u32 b)
{ return __builtin_amdgcn_permlane32_swap(a, b, false, false); }

static __device__ __forceinline__ bf16x8 mkfrag(u32 w0, u32 w1, u32 w2, u32 w3)
{
    union { u32 u[4]; bf16x8 v; } c;
    c.u[0] = w0; c.u[1] = w1; c.u[2] = w2; c.u[3] = w3;
    return c.v;
}
static __device__ __forceinline__ bf16x8 u4frag(uint4 u)
{ union { uint4 a; bf16x8 v; } c; c.a = u; return c.v; }

static __device__ __forceinline__ f32x16 mfma(bf16x8 a, bf16x8 b, f32x16 c)
{ return __builtin_amdgcn_mfma_f32_32x32x16_bf16(a, b, c, 0, 0, 0); }

// stable softplus; 1+t in (1,2] -> __logf exact there (round-8 proven)
static __device__ __forceinline__ float softplus(float a)
{ return fmaxf(a, 0.0f) + __logf(1.0f + __expf(-fabsf(a))); }

// ---- per-slot weight-fragment gather (r13 fold) -----------------------------

static __device__ __forceinline__ uint4 build_frag_slot(
    const float* __restrict__ pp, int f, int l)
{
    const int c31 = l & 31;
    const int g   = l >> 5;
    float tv[8];
#pragma unroll
    for (int j = 0; j < 8; ++j) tv[j] = 0.0f;

    if (f < 12) {
        const int L = f / 6, t = (f % 6) / 3, s = f % 3;
        const int wb = 108 + L * 1332;
        const int r  = c31 + 32 * t;                 // outfeat row
        if (r < 36) {
#pragma unroll
            for (int j = 0; j < 8; ++j) {
                const int i = 16 * s + 8 * g + j;    // infeat (k)
                if (i < 36)       tv[j] = pp[wb + 36 * r + i] * INV2PI;
                else if (i == 36) tv[j] = pp[wb + 1296 + r] * INV2PI;  // bias
            }
        }
    } else {
        const int t = f - 12;                        // layer-1 tile
        const int r = c31 + 32 * t;
        if (r < 36 && g == 0) {
            tv[0] = pp[2 * r]     * INV2PI;   // k=0: w_x
            tv[1] = pp[2 * r + 1] * INV2PI;   // k=1: w_y
            tv[2] = pp[72 + r]    * INV2PI;   // k=2: bias (h=1 slot)
        }
    }
    uint4 o;
    o.x = pk2(tv[0], tv[1]); o.y = pk2(tv[2], tv[3]);
    o.z = pk2(tv[4], tv[5]); o.w = pk2(tv[6], tv[7]);
    return o;
}

// ---- B-fragment builder: sin(D) -> next-layer B frag (all v_sin) ------------

static __device__ __forceinline__ void buildB(const f32x16& d1, const f32x16& d2,
                                              u32 biasw, u32 (&F)[12])
{
    float s1[16];
#pragma unroll
    for (int r = 0; r < 16; ++r) s1[r] = sin_rev(d1[r]);
    u32 c[8];
#pragma unroll
    for (int q = 0; q < 8; ++q) c[q] = pk2(s1[2 * q], s1[2 * q + 1]);
    const u32 q0 = pk2(sin_rev(d2[0]), sin_rev(d2[1]));
    const u32 q1 = pk2(sin_rev(d2[2]), sin_rev(d2[3]));

    u32x2 r;
    r = plsw(c[0], c[2]); F[0] = r.x; F[2] = r.y;   // kstep0
    r = plsw(c[1], c[3]); F[1] = r.x; F[3] = r.y;
    r = plsw(c[4], c[6]); F[4] = r.x; F[6] = r.y;   // kstep1
    r = plsw(c[5], c[7]); F[5] = r.x; F[7] = r.y;
    F[8] = q0; F[9] = q1; F[10] = biasw; F[11] = 0; // kstep2
}

// ---- one point-tile: L1 mfma -> L2 -> L3 -> final on VALU -------------------
// fwl = &lds_fw[lane]: mid-layer frag f read as fwl[f*64] (ds_read_b128,
// conflict-free). w4c = &lds_w4[lane]: final-layer weight r at w4c[r*64].

static __device__ __forceinline__ float tile_forward(
    const uint4* fwl, bf16x8 w1a, bf16x8 w1b, bf16x8 bl1,
    const float* w4c, float b4, u32 biasw, const f32x16& z)
{
    // layer 1 (K=3 in one kstep); D in revolutions
    f32x16 d1 = mfma(w1a, bl1, z);
    f32x16 d2 = mfma(w1b, bl1, z);

    // layer 2 (frags 0..5)
    u32 F[12];
    buildB(d1, d2, biasw, F);
    d1 = z; d2 = z;
#pragma unroll
    for (int s = 0; s < 3; ++s) {
        const bf16x8 bf = mkfrag(F[4*s], F[4*s+1], F[4*s+2], F[4*s+3]);
        d1 = mfma(u4frag(fwl[s * 64]),       bf, d1);
        d2 = mfma(u4frag(fwl[(3 + s) * 64]), bf, d2);
    }
    // layer 3 (frags 6..11)
    u32 F2[12];
    buildB(d1, d2, biasw, F2);
    d1 = z; d2 = z;
#pragma unroll
    for (int s = 0; s < 3; ++s) {
        const bf16x8 bf = mkfrag(F2[4*s], F2[4*s+1], F2[4*s+2], F2[4*s+3]);
        d1 = mfma(u4frag(fwl[(6 + s) * 64]), bf, d1);
        d2 = mfma(u4frag(fwl[(9 + s) * 64]), bf, d2);
    }
    // final layer on VALU: sin#3 (rev) + f32 dot over this lane's feats
    float a0 = 0.0f, a1 = 0.0f;
#pragma unroll
    for (int r = 0; r < 16; r += 2) {
        a0 = fmaf(w4c[r * 64],       sin_rev(d1[r]),     a0);
        a1 = fmaf(w4c[(r + 1) * 64], sin_rev(d1[r + 1]), a1);
    }
#pragma unroll
    for (int r = 0; r < 4; r += 2) {
        a0 = fmaf(w4c[(16 + r) * 64], sin_rev(d2[r]),     a0);
        a1 = fmaf(w4c[(17 + r) * 64], sin_rev(d2[r + 1]), a1);
    }
    const float part = a0 + a1;
    // pair-reduce: lane l (<32) adds partner l+32's partial
    const u32x2 t = plsw(__float_as_uint(part), __float_as_uint(part));
    const float tot = part + __uint_as_float(t.y) + b4;
    return softplus(tot);   // valid at g0 lanes
}

// ---- main kernel ------------------------------------------------------------

__global__ __launch_bounds__(BLOCK) void mlp_mfma_kernel(
    const float* __restrict__ x,
    const float* __restrict__ params,     // original (32,2809)
    float* __restrict__ out)
{
    __shared__ uint4 lds_fw[14 * 64];
    __shared__ float lds_w4[20 * 64];     // [r][lane]

    const int lane = threadIdx.x & 63;
    const int wave = threadIdx.x >> 6;
    const int b    = blockIdx.y;

    const float* pp = params + (size_t)b * NPAR;

    // ---- phase 0: cooperative frag + W4-table build into LDS ----
#pragma unroll
    for (int k = 0; k < 2; ++k) {
        const int sid = threadIdx.x + BLOCK * k;   // 0..1023; 896 real slots
        if (sid < 896)
            lds_fw[sid] = build_frag_slot(pp, sid >> 6, sid & 63);
    }
#pragma unroll
    for (int k = 0; k < 3; ++k) {
        const int sid = threadIdx.x + BLOCK * k;   // 0..1535; 1280 real slots
        if (sid < 1280) {
            const int r  = sid >> 6;
            const int l  = sid & 63;
            const int gg = l >> 5;
            float v = 0.0f;
            if (r < 16)       v = pp[2772 + ((r & 3) + 8 * (r >> 2) + 4 * gg)];
            else if (gg == 0) v = pp[2772 + 32 + (r - 16)];
            lds_w4[sid] = v;
        }
    }
    __syncthreads();

    // layer-1 frags only in registers (8 VGPRs)
    const bf16x8 w1a = u4frag(lds_fw[12 * 64 + lane]);
    const bf16x8 w1b = u4frag(lds_fw[13 * 64 + lane]);
    const uint4* fwl = &lds_fw[lane];
    const float* w4c = &lds_w4[lane];

    const float b4 = pp[2808];
    const u32 biasw = pk2(1.0f, 0.0f);

    f32x16 z;
#pragma unroll
    for (int i = 0; i < 16; ++i) z[i] = 0.0f;

    // ---- x-load software pipeline (r19): iter+1's load before iter's use ----
    const int nbase = blockIdx.x * (64 * ITERS * WPB) + wave * (64 * ITERS) + lane;
    const float2* xp = reinterpret_cast<const float2*>(x);

    float2 xv = xp[nbase];

#pragma unroll 1
    for (int it = 0; it < ITERS; ++it) {
        // prefetch next iter's point (clamped re-load of same on last iter)
        const int itn = (it + 1 < ITERS) ? it + 1 : it;
        const float2 xvn = xp[nbase + itn * 64];

        // layer-1 B frags: own point (tile A) / partner's point (tile B).
        const u32 pxy  = pk2(xv.x, xv.y);
        const u32 pxyB = plsw(pxy, pxy).y;

        const float spA = tile_forward(fwl, w1a, w1b, mkfrag(pxy,  biasw, 0, 0),
                                       w4c, b4, biasw, z);
        const float spB = tile_forward(fwl, w1a, w1b, mkfrag(pxyB, biasw, 0, 0),
                                       w4c, b4, biasw, z);

        // merged store (tile A -> lanes 0..31, B -> 32..63)
        const u32x2 r = plsw(__float_as_uint(spA), __float_as_uint(spB));
        out[(size_t)b * NPTS + nbase + it * 64] = __uint_as_float(r.x);
        xv = xvn;
    }
}

extern "C" void kernel_launch(void* const* d_in, const int* in_sizes, int n_in,
                              void* d_out, int out_size, void* d_ws, size_t ws_size,
                              hipStream_t stream)
{
    const float* x = (const float*)d_in[0];
    const float* params = (const float*)d_in[1];
    float* out = (float*)d_out;

    mlp_mfma_kernel<<<dim3(NPTS / (64 * ITERS * WPB), NBATCH), dim3(BLOCK), 0, stream>>>(
        x, params, out);
}

// Round 23
// 41.082 us; speedup vs baseline: 4.8427x; 1.1063x over previous
//
#include <hip/hip_runtime.h>
#include <math.h>

// Per-batch MLP 2->36->36->36->1 (sin,sin,sin,softplus) on MFMA, round 23.
// x: (65536,2) f32; params: (32,2809) f32; out: (32,65536) f32.
//
// Formulation per 32-point tile: D = W * h^T, v_mfma_f32_32x32x16_bf16.
// D layout (HW-verified): col=lane&31 (point), feat=(r&3)+8*(r>>2)+4*(lane>>5).
//
// Round-23: FINAL -- exact revert to the r19 configuration (41.1us, best).
// r22 decode: allocator floor is ~76 VGPR for this code shape (buildB
// transient pressure), so the 64-reg band is unreachable without spill;
// per-use LDS frag reads cost more than the occupancy they'd buy.
// Structural constraint (session conclusion): 108 sins/point is fixed by
// the algorithm; v_sin runs ~12cyc/wave on the SHARED VALU issue port
// (r18: trans and FMA work do not overlap -- hybrid = linear mix). Port
// roofline ~27us; measured 41us carries a ~1.5x dep-stall factor that
// occupancy cannot remove: more blocks (r15/r20 neutral), in-wave ILP
// (r16 neutral), launch_bounds forcing (r14/r21 -> VGPR=32 spill, 500MB),
// natural reg slimming (r22 -> 76 regs, slower). 6.2x over baseline.
// Frozen: RTZ pk2 (r12), INV2PI fold + v_sin revolutions (r13), plsw
// exchanges (r6+), LDS frag build (r6), x prefetch + BLOCK=512 (r19),
// serial tiles (r9), f32 final dot (r9), softplus via __logf (r8).
// Condemned: cvt_pk_bf16, launch_bounds-forcing, poly/hybrid sin.

#define NPTS   65536
#define NBATCH 32
#define NPAR   2809
#define ITERS  8       // points per wave = 64 * ITERS
#define BLOCK  512
#define WPB    (BLOCK / 64)    // waves per block = 8
#define INV2PI 0.15915494309189535f

typedef float        f32x16 __attribute__((ext_vector_type(16)));
typedef short        bf16x8 __attribute__((ext_vector_type(8)));
typedef unsigned int u32;
typedef unsigned int u32x2 __attribute__((ext_vector_type(2)));

// 1-inst pack {bf16_rtz(lo), bf16_rtz(hi)} (r12-proven)
static __device__ __forceinline__ u32 pk2(float lo, float hi)
{
    return __builtin_amdgcn_perm(__float_as_uint(hi), __float_as_uint(lo),
                                 0x07060302u);
}

// raw v_sin_f32: sin(2*pi*y), y in revolutions (|y| <= ~0.65 here)
static __device__ __forceinline__ float sin_rev(float y)
{ return __builtin_amdgcn_sinf(y); }

// swap a's hi-32-lanes with b's lo-32-lanes (proven rounds 6-22)
static __device__ __forceinline__ u32x2 plsw(u32 a, u32 b)
{ return __builtin_amdgcn_permlane32_swap(a, b, false, false); }

static __device__ __forceinline__ bf16x8 mkfrag(u32 w0, u32 w1, u32 w2, u32 w3)
{
    union { u32 u[4]; bf16x8 v; } c;
    c.u[0] = w0; c.u[1] = w1; c.u[2] = w2; c.u[3] = w3;
    return c.v;
}
static __device__ __forceinline__ bf16x8 u4frag(uint4 u)
{ union { uint4 a; bf16x8 v; } c; c.a = u; return c.v; }

static __device__ __forceinline__ f32x16 mfma(bf16x8 a, bf16x8 b, f32x16 c)
{ return __builtin_amdgcn_mfma_f32_32x32x16_bf16(a, b, c, 0, 0, 0); }

// stable softplus; 1+t in (1,2] -> __logf exact there (round-8 proven)
static __device__ __forceinline__ float softplus(float a)
{ return fmaxf(a, 0.0f) + __logf(1.0f + __expf(-fabsf(a))); }

// ---- per-slot weight-fragment gather (r13 fold) -----------------------------

static __device__ __forceinline__ uint4 build_frag_slot(
    const float* __restrict__ pp, int f, int l)
{
    const int c31 = l & 31;
    const int g   = l >> 5;
    float tv[8];
#pragma unroll
    for (int j = 0; j < 8; ++j) tv[j] = 0.0f;

    if (f < 12) {
        const int L = f / 6, t = (f % 6) / 3, s = f % 3;
        const int wb = 108 + L * 1332;
        const int r  = c31 + 32 * t;                 // outfeat row
        if (r < 36) {
#pragma unroll
            for (int j = 0; j < 8; ++j) {
                const int i = 16 * s + 8 * g + j;    // infeat (k)
                if (i < 36)       tv[j] = pp[wb + 36 * r + i] * INV2PI;
                else if (i == 36) tv[j] = pp[wb + 1296 + r] * INV2PI;  // bias
            }
        }
    } else {
        const int t = f - 12;                        // layer-1 tile
        const int r = c31 + 32 * t;
        if (r < 36 && g == 0) {
            tv[0] = pp[2 * r]     * INV2PI;   // k=0: w_x
            tv[1] = pp[2 * r + 1] * INV2PI;   // k=1: w_y
            tv[2] = pp[72 + r]    * INV2PI;   // k=2: bias (h=1 slot)
        }
    }
    uint4 o;
    o.x = pk2(tv[0], tv[1]); o.y = pk2(tv[2], tv[3]);
    o.z = pk2(tv[4], tv[5]); o.w = pk2(tv[6], tv[7]);
    return o;
}

// ---- B-fragment builder: sin(D) -> next-layer B frag (all v_sin) ------------

static __device__ __forceinline__ void buildB(const f32x16& d1, const f32x16& d2,
                                              u32 biasw, u32 (&F)[12])
{
    float s1[16];
#pragma unroll
    for (int r = 0; r < 16; ++r) s1[r] = sin_rev(d1[r]);
    u32 c[8];
#pragma unroll
    for (int q = 0; q < 8; ++q) c[q] = pk2(s1[2 * q], s1[2 * q + 1]);
    const u32 q0 = pk2(sin_rev(d2[0]), sin_rev(d2[1]));
    const u32 q1 = pk2(sin_rev(d2[2]), sin_rev(d2[3]));

    u32x2 r;
    r = plsw(c[0], c[2]); F[0] = r.x; F[2] = r.y;   // kstep0
    r = plsw(c[1], c[3]); F[1] = r.x; F[3] = r.y;
    r = plsw(c[4], c[6]); F[4] = r.x; F[6] = r.y;   // kstep1
    r = plsw(c[5], c[7]); F[5] = r.x; F[7] = r.y;
    F[8] = q0; F[9] = q1; F[10] = biasw; F[11] = 0; // kstep2
}

// ---- BOTH point-tiles through the net, chains interleaved (r16) -------------

static __device__ __forceinline__ u32 tile_pair(
    const uint4 (&W)[12], bf16x8 w1a, bf16x8 w1b, bf16x8 blA, bf16x8 blB,
    const float (&w4a)[16], const float (&w4b)[4], float b4,
    u32 biasw, const f32x16& z)
{
    // layer 1 (K=3 in one kstep); D in revolutions
    f32x16 a1 = mfma(w1a, blA, z);
    f32x16 b1 = mfma(w1a, blB, z);
    f32x16 a2 = mfma(w1b, blA, z);
    f32x16 b2 = mfma(w1b, blB, z);

    // layer 2 (frags 0..5)
    u32 FA[12], FB[12];
    buildB(a1, a2, biasw, FA);
    buildB(b1, b2, biasw, FB);
    a1 = z; a2 = z; b1 = z; b2 = z;
#pragma unroll
    for (int s = 0; s < 3; ++s) {
        const bf16x8 fa = mkfrag(FA[4*s], FA[4*s+1], FA[4*s+2], FA[4*s+3]);
        const bf16x8 fb = mkfrag(FB[4*s], FB[4*s+1], FB[4*s+2], FB[4*s+3]);
        a1 = mfma(u4frag(W[s]),     fa, a1);
        b1 = mfma(u4frag(W[s]),     fb, b1);
        a2 = mfma(u4frag(W[3 + s]), fa, a2);
        b2 = mfma(u4frag(W[3 + s]), fb, b2);
    }

    // layer 3 (frags 6..11)
    buildB(a1, a2, biasw, FA);
    buildB(b1, b2, biasw, FB);
    a1 = z; a2 = z; b1 = z; b2 = z;
#pragma unroll
    for (int s = 0; s < 3; ++s) {
        const bf16x8 fa = mkfrag(FA[4*s], FA[4*s+1], FA[4*s+2], FA[4*s+3]);
        const bf16x8 fb = mkfrag(FB[4*s], FB[4*s+1], FB[4*s+2], FB[4*s+3]);
        a1 = mfma(u4frag(W[6 + s]), fa, a1);
        b1 = mfma(u4frag(W[6 + s]), fb, b1);
        a2 = mfma(u4frag(W[9 + s]), fa, a2);
        b2 = mfma(u4frag(W[9 + s]), fb, b2);
    }

    // final layer on VALU: sin#3 (rev) + f32 dot, both tiles interleaved
    float sA0 = 0.0f, sA1 = 0.0f, sB0 = 0.0f, sB1 = 0.0f;
#pragma unroll
    for (int r = 0; r < 16; r += 2) {
        sA0 = fmaf(w4a[r],     sin_rev(a1[r]),     sA0);
        sB0 = fmaf(w4a[r],     sin_rev(b1[r]),     sB0);
        sA1 = fmaf(w4a[r + 1], sin_rev(a1[r + 1]), sA1);
        sB1 = fmaf(w4a[r + 1], sin_rev(b1[r + 1]), sB1);
    }
#pragma unroll
    for (int r = 0; r < 4; r += 2) {
        sA0 = fmaf(w4b[r],     sin_rev(a2[r]),     sA0);
        sB0 = fmaf(w4b[r],     sin_rev(b2[r]),     sB0);
        sA1 = fmaf(w4b[r + 1], sin_rev(a2[r + 1]), sA1);
        sB1 = fmaf(w4b[r + 1], sin_rev(b2[r + 1]), sB1);
    }
    const float pA = sA0 + sA1;
    const float pB = sB0 + sB1;
    // pair-reduce: lane l (<32) adds partner l+32's partial
    const u32x2 tA = plsw(__float_as_uint(pA), __float_as_uint(pA));
    const u32x2 tB = plsw(__float_as_uint(pB), __float_as_uint(pB));
    const float spA = softplus(pA + __uint_as_float(tA.y) + b4);
    const float spB = softplus(pB + __uint_as_float(tB.y) + b4);

    // merged store word (tile A -> lanes 0..31, B -> 32..63)
    return plsw(__float_as_uint(spA), __float_as_uint(spB)).x;
}

// ---- main kernel ------------------------------------------------------------

__global__ __launch_bounds__(BLOCK) void mlp_mfma_kernel(
    const float* __restrict__ x,
    const float* __restrict__ params,     // original (32,2809)
    float* __restrict__ out)
{
    __shared__ uint4 lds_fw[14 * 64];

    const int lane = threadIdx.x & 63;
    const int wave = threadIdx.x >> 6;
    const int b    = blockIdx.y;
    const int g    = lane >> 5;

    const float* pp = params + (size_t)b * NPAR;

    // ---- phase 0: cooperative frag build into LDS (once per block) ----
#pragma unroll
    for (int k = 0; k < 2; ++k) {
        const int sid = threadIdx.x + BLOCK * k;   // 0..1023; 896 real slots
        if (sid < 896)
            lds_fw[sid] = build_frag_slot(pp, sid >> 6, sid & 63);
    }
    __syncthreads();

    uint4 W[12];
#pragma unroll
    for (int f = 0; f < 12; ++f)
        W[f] = lds_fw[f * 64 + lane];
    const bf16x8 w1a = u4frag(lds_fw[12 * 64 + lane]);
    const bf16x8 w1b = u4frag(lds_fw[13 * 64 + lane]);

    // ---- per-lane W4 in f32 (UNFOLDED), mapping (r&3)+8*(r>>2)+4g ----
    float w4a[16];
#pragma unroll
    for (int r = 0; r < 16; ++r)
        w4a[r] = pp[2772 + ((r & 3) + 8 * (r >> 2) + 4 * g)];
    float w4b[4];
#pragma unroll
    for (int r = 0; r < 4; ++r)
        w4b[r] = (g == 0) ? pp[2772 + 32 + r] : 0.0f;
    const float b4 = pp[2808];

    const u32 biasw = pk2(1.0f, 0.0f);

    f32x16 z;
#pragma unroll
    for (int i = 0; i < 16; ++i) z[i] = 0.0f;

    // ---- x-load software pipeline (r19): iter+1's load before iter's use ----
    const int nbase = blockIdx.x * (64 * ITERS * WPB) + wave * (64 * ITERS) + lane;
    const float2* xp = reinterpret_cast<const float2*>(x);

    float2 xv = xp[nbase];

#pragma unroll 1
    for (int it = 0; it < ITERS; ++it) {
        // prefetch next iter's point (clamped re-load of same on last iter)
        const int itn = (it + 1 < ITERS) ? it + 1 : it;
        const float2 xvn = xp[nbase + itn * 64];

        // layer-1 B frags: own point (tile A) / partner's point (tile B).
        const u32 pxy  = pk2(xv.x, xv.y);
        const u32 pxyB = plsw(pxy, pxy).y;

        const u32 outw = tile_pair(W, w1a, w1b,
                                   mkfrag(pxy,  biasw, 0, 0),
                                   mkfrag(pxyB, biasw, 0, 0),
                                   w4a, w4b, b4, biasw, z);

        out[(size_t)b * NPTS + nbase + it * 64] = __uint_as_float(outw);
        xv = xvn;
    }
}

extern "C" void kernel_launch(void* const* d_in, const int* in_sizes, int n_in,
                              void* d_out, int out_size, void* d_ws, size_t ws_size,
                              hipStream_t stream)
{
    const float* x = (const float*)d_in[0];
    const float* params = (const float*)d_in[1];
    float* out = (float*)d_out;

    mlp_mfma_kernel<<<dim3(NPTS / (64 * ITERS * WPB), NBATCH), dim3(BLOCK), 0, stream>>>(
        x, params, out);
}